// Round 2
// baseline (632.287 us; speedup 1.0000x reference)
//
#include <hip/hip_runtime.h>
#include <hip/hip_bf16.h>

// out = blur(img[0]/max)*max == blur(img[0]) (linear blur; normalization cancels).
// Separable 25-tap Gaussian, sigma=4, replicate padding, C=3, H=W=4096, fp32.

#define IMG_W 4096
#define IMG_H 4096
#define N_CH  3
#define HALF  12
#define KSZ   25

#define TILE_W 96                 // output tile width
#define TILE_H 64                 // output tile height
#define COLS   (TILE_W + 2*HALF)  // 120 intermediate columns
#define LDS_STRIDE 124            // +4 floats: keeps 16B row alignment, 124%32=28 spreads banks
#define GRP_ROWS 16               // output rows per vertical task
#define N_GRP    4                // 4 row groups -> 64 rows
#define VROWS (GRP_ROWS + 2*HALF) // 40 input rows per vertical task
#define VCOLS2 (COLS/2)           // 60 float2 columns
#define HCHUNK 24                 // output px per horizontal task (96/4)
#define HREAD  (HCHUNK + 2*HALF)  // 48 floats = 12 x b128

__device__ __constant__ float kW[KSZ] = {
    0.00110988f, 0.00227883f, 0.00438965f, 0.00794860f, 0.01352109f,
    0.02160664f, 0.03243540f, 0.04574124f, 0.06059730f, 0.07541456f,
    0.08816855f, 0.09683420f, 0.09990806f, 0.09683420f, 0.08816855f,
    0.07541456f, 0.06059730f, 0.04574124f, 0.03243540f, 0.02160664f,
    0.01352109f, 0.00794860f, 0.00438965f, 0.00227883f, 0.00110988f
};

__global__ __launch_bounds__(256, 5)
void gauss_blur_fused(const float* __restrict__ img, float* __restrict__ out)
{
    __shared__ float inter[TILE_H * LDS_STRIDE]; // 64*124*4 = 31744 B -> 5 blocks/CU

    const int tid = threadIdx.x;
    const int x0  = blockIdx.x * TILE_W;
    const int y0  = blockIdx.y * TILE_H;
    const int c   = blockIdx.z;

    const float* __restrict__ src = img + (size_t)c * IMG_W * IMG_H;
    float* __restrict__ dst       = out + (size_t)c * IMG_W * IMG_H;

    // ---------------- vertical pass: float2 columns, register sliding window
    if (tid < VCOLS2 * N_GRP) {          // 240 active
        const int c2 = tid % VCOLS2;     // 0..59
        const int g  = tid / VCOLS2;     // 0..3
        const int gx = x0 - HALF + 2 * c2;       // even; pairs never straddle an edge
        const int ybase = y0 + g * GRP_ROWS - HALF;
        const int ldscol = 2 * c2;

        float2 w[KSZ];                   // 25-float2 sliding window (50 VGPR)

        if (gx >= 0 && gx <= IMG_W - 2) {
            // x-interior: vector loads
            if (ybase >= 0 && ybase + VROWS <= IMG_H) {
                // y-interior fast path
                const float* p = src + (size_t)ybase * IMG_W + gx;
                #pragma unroll
                for (int i = 0; i < KSZ - 1; ++i)
                    w[i] = *(const float2*)(p + (size_t)i * IMG_W);
                #pragma unroll
                for (int i = 0; i < GRP_ROWS; ++i) {
                    w[KSZ - 1] = *(const float2*)(p + (size_t)(i + KSZ - 1) * IMG_W);
                    float2 acc; acc.x = 0.f; acc.y = 0.f;
                    #pragma unroll
                    for (int k = 0; k < KSZ; ++k) {
                        acc.x += kW[k] * w[k].x;
                        acc.y += kW[k] * w[k].y;
                    }
                    *(float2*)&inter[(g * GRP_ROWS + i) * LDS_STRIDE + ldscol] = acc;
                    #pragma unroll
                    for (int k = 0; k < KSZ - 1; ++k) w[k] = w[k + 1]; // renamed away
                }
            } else {
                // y-edge: clamp rows
                #pragma unroll
                for (int i = 0; i < KSZ - 1; ++i) {
                    int gy = ybase + i; gy = gy < 0 ? 0 : (gy > IMG_H - 1 ? IMG_H - 1 : gy);
                    w[i] = *(const float2*)(src + (size_t)gy * IMG_W + gx);
                }
                #pragma unroll
                for (int i = 0; i < GRP_ROWS; ++i) {
                    int gy = ybase + i + KSZ - 1;
                    gy = gy < 0 ? 0 : (gy > IMG_H - 1 ? IMG_H - 1 : gy);
                    w[KSZ - 1] = *(const float2*)(src + (size_t)gy * IMG_W + gx);
                    float2 acc; acc.x = 0.f; acc.y = 0.f;
                    #pragma unroll
                    for (int k = 0; k < KSZ; ++k) {
                        acc.x += kW[k] * w[k].x;
                        acc.y += kW[k] * w[k].y;
                    }
                    *(float2*)&inter[(g * GRP_ROWS + i) * LDS_STRIDE + ldscol] = acc;
                    #pragma unroll
                    for (int k = 0; k < KSZ - 1; ++k) w[k] = w[k + 1];
                }
            }
        } else {
            // x-edge: whole pair clamps to the same edge column (gx always even)
            const int gc = gx < 0 ? 0 : IMG_W - 1;
            #pragma unroll
            for (int i = 0; i < KSZ - 1; ++i) {
                int gy = ybase + i; gy = gy < 0 ? 0 : (gy > IMG_H - 1 ? IMG_H - 1 : gy);
                float v = src[(size_t)gy * IMG_W + gc];
                w[i].x = v; w[i].y = v;
            }
            #pragma unroll
            for (int i = 0; i < GRP_ROWS; ++i) {
                int gy = ybase + i + KSZ - 1;
                gy = gy < 0 ? 0 : (gy > IMG_H - 1 ? IMG_H - 1 : gy);
                float v = src[(size_t)gy * IMG_W + gc];
                w[KSZ - 1].x = v; w[KSZ - 1].y = v;
                float2 acc; acc.x = 0.f; acc.y = 0.f;
                #pragma unroll
                for (int k = 0; k < KSZ; ++k) {
                    acc.x += kW[k] * w[k].x;
                    acc.y += kW[k] * w[k].y;
                }
                *(float2*)&inter[(g * GRP_ROWS + i) * LDS_STRIDE + ldscol] = acc;
                #pragma unroll
                for (int k = 0; k < KSZ - 1; ++k) w[k] = w[k + 1];
            }
        }
    }
    __syncthreads();

    // ---------------- horizontal pass: b128 LDS reads, float4 stores
    {
        const int row   = tid >> 2;        // 0..63
        const int chunk = tid & 3;         // 0..3
        const int xl    = chunk * HCHUNK;  // 0,24,48,72 -> 96c bytes, 16B aligned

        float v[HREAD]; // 48
        const float4* lp = (const float4*)&inter[row * LDS_STRIDE + xl];
        #pragma unroll
        for (int i = 0; i < HREAD / 4; ++i) {
            float4 t = lp[i];
            v[4 * i + 0] = t.x; v[4 * i + 1] = t.y;
            v[4 * i + 2] = t.z; v[4 * i + 3] = t.w;
        }

        float acc[HCHUNK];
        #pragma unroll
        for (int j = 0; j < HCHUNK; ++j) {
            float a = 0.f;
            #pragma unroll
            for (int k = 0; k < KSZ; ++k)
                a += kW[k] * v[j + k];
            acc[j] = a;
        }

        const size_t rowbase = (size_t)(y0 + row) * IMG_W;
        const int gx0 = x0 + xl;
        #pragma unroll
        for (int j = 0; j < HCHUNK / 4; ++j) {
            const int gx = gx0 + 4 * j;    // multiple of 4
            if (gx < IMG_W) {
                float4 o;
                o.x = acc[4 * j + 0]; o.y = acc[4 * j + 1];
                o.z = acc[4 * j + 2]; o.w = acc[4 * j + 3];
                *(float4*)&dst[rowbase + gx] = o;
            }
        }
    }
}

extern "C" void kernel_launch(void* const* d_in, const int* in_sizes, int n_in,
                              void* d_out, int out_size, void* d_ws, size_t ws_size,
                              hipStream_t stream)
{
    const float* img = (const float*)d_in[0];
    float* out = (float*)d_out;

    dim3 grid((IMG_W + TILE_W - 1) / TILE_W,  // 43
              IMG_H / TILE_H,                 // 64
              N_CH);                          // 3
    dim3 block(256);
    gauss_blur_fused<<<grid, block, 0, stream>>>(img, out);
}

// Round 3
// 394.424 us; speedup vs baseline: 1.6031x; 1.6031x over previous
//
#include <hip/hip_runtime.h>
#include <hip/hip_bf16.h>

// out = blur(img[0]/max)*max == blur(img[0]) (linear blur; normalization cancels).
// Separable 25-tap Gaussian, sigma=4, replicate padding, C=3, H=W=4096, fp32.

#define IMG_W 4096
#define IMG_H 4096
#define N_CH  3
#define HALF  12
#define KSZ   25

#define TILE_W 96                 // output tile width
#define TILE_H 64                 // output tile height
#define COLS   (TILE_W + 2*HALF)  // 120 intermediate columns
#define LDS_STRIDE 124            // 16B-aligned rows; 124%32=28 spreads banks
#define GRP_ROWS 16               // output rows per vertical task
#define N_GRP    4                // 4 row groups -> 64 rows
#define VROWS (GRP_ROWS + 2*HALF) // 40 input rows per vertical task
#define VCOLS2 (COLS/2)           // 60 float2 columns
#define HCHUNK 24                 // output px per horizontal task (96/4)
#define HREAD  (HCHUNK + 2*HALF)  // 48 floats = 12 x b128

// NOTE: no min-waves hint. Round-2's __launch_bounds__(256,5) forced VGPR=48,
// spilling ~40 floats/thread to scratch -> WRITE_SIZE 204MB -> 1.06GB, 1.6x slower.
// Live sets here need ~60-100 VGPRs; let the allocator have them.

__device__ __constant__ float kW[KSZ] = {
    0.00110988f, 0.00227883f, 0.00438965f, 0.00794860f, 0.01352109f,
    0.02160664f, 0.03243540f, 0.04574124f, 0.06059730f, 0.07541456f,
    0.08816855f, 0.09683420f, 0.09990806f, 0.09683420f, 0.08816855f,
    0.07541456f, 0.06059730f, 0.04574124f, 0.03243540f, 0.02160664f,
    0.01352109f, 0.00794860f, 0.00438965f, 0.00227883f, 0.00110988f
};

__global__ __launch_bounds__(256)
void gauss_blur_fused(const float* __restrict__ img, float* __restrict__ out)
{
    __shared__ float inter[TILE_H * LDS_STRIDE]; // 64*124*4 = 31744 B

    const int tid = threadIdx.x;
    const int x0  = blockIdx.x * TILE_W;
    const int y0  = blockIdx.y * TILE_H;
    const int c   = blockIdx.z;

    const float* __restrict__ src = img + (size_t)c * IMG_W * IMG_H;
    float* __restrict__ dst       = out + (size_t)c * IMG_W * IMG_H;

    // ---------------- vertical pass: float2 columns, register sliding window
    if (tid < VCOLS2 * N_GRP) {          // 240 active
        const int c2 = tid % VCOLS2;     // 0..59
        const int g  = tid / VCOLS2;     // 0..3
        const int gx = x0 - HALF + 2 * c2;       // even; pairs never straddle an edge
        const int ybase = y0 + g * GRP_ROWS - HALF;
        const int ldscol = 2 * c2;

        float2 w[KSZ];                   // 25-float2 sliding window (~50 VGPR)

        if (gx >= 0 && gx <= IMG_W - 2) {
            if (ybase >= 0 && ybase + VROWS <= IMG_H) {
                // interior fast path
                const float* p = src + (size_t)ybase * IMG_W + gx;
                #pragma unroll
                for (int i = 0; i < KSZ - 1; ++i)
                    w[i] = *(const float2*)(p + (size_t)i * IMG_W);
                #pragma unroll
                for (int i = 0; i < GRP_ROWS; ++i) {
                    w[KSZ - 1] = *(const float2*)(p + (size_t)(i + KSZ - 1) * IMG_W);
                    float2 acc; acc.x = 0.f; acc.y = 0.f;
                    #pragma unroll
                    for (int k = 0; k < KSZ; ++k) {
                        acc.x += kW[k] * w[k].x;
                        acc.y += kW[k] * w[k].y;
                    }
                    *(float2*)&inter[(g * GRP_ROWS + i) * LDS_STRIDE + ldscol] = acc;
                    #pragma unroll
                    for (int k = 0; k < KSZ - 1; ++k) w[k] = w[k + 1]; // renamed away
                }
            } else {
                // y-edge: clamp rows
                #pragma unroll
                for (int i = 0; i < KSZ - 1; ++i) {
                    int gy = ybase + i; gy = gy < 0 ? 0 : (gy > IMG_H - 1 ? IMG_H - 1 : gy);
                    w[i] = *(const float2*)(src + (size_t)gy * IMG_W + gx);
                }
                #pragma unroll
                for (int i = 0; i < GRP_ROWS; ++i) {
                    int gy = ybase + i + KSZ - 1;
                    gy = gy < 0 ? 0 : (gy > IMG_H - 1 ? IMG_H - 1 : gy);
                    w[KSZ - 1] = *(const float2*)(src + (size_t)gy * IMG_W + gx);
                    float2 acc; acc.x = 0.f; acc.y = 0.f;
                    #pragma unroll
                    for (int k = 0; k < KSZ; ++k) {
                        acc.x += kW[k] * w[k].x;
                        acc.y += kW[k] * w[k].y;
                    }
                    *(float2*)&inter[(g * GRP_ROWS + i) * LDS_STRIDE + ldscol] = acc;
                    #pragma unroll
                    for (int k = 0; k < KSZ - 1; ++k) w[k] = w[k + 1];
                }
            }
        } else {
            // x-edge: whole pair clamps to the same edge column (gx always even)
            const int gc = gx < 0 ? 0 : IMG_W - 1;
            #pragma unroll
            for (int i = 0; i < KSZ - 1; ++i) {
                int gy = ybase + i; gy = gy < 0 ? 0 : (gy > IMG_H - 1 ? IMG_H - 1 : gy);
                float v = src[(size_t)gy * IMG_W + gc];
                w[i].x = v; w[i].y = v;
            }
            #pragma unroll
            for (int i = 0; i < GRP_ROWS; ++i) {
                int gy = ybase + i + KSZ - 1;
                gy = gy < 0 ? 0 : (gy > IMG_H - 1 ? IMG_H - 1 : gy);
                float v = src[(size_t)gy * IMG_W + gc];
                w[KSZ - 1].x = v; w[KSZ - 1].y = v;
                float2 acc; acc.x = 0.f; acc.y = 0.f;
                #pragma unroll
                for (int k = 0; k < KSZ; ++k) {
                    acc.x += kW[k] * w[k].x;
                    acc.y += kW[k] * w[k].y;
                }
                *(float2*)&inter[(g * GRP_ROWS + i) * LDS_STRIDE + ldscol] = acc;
                #pragma unroll
                for (int k = 0; k < KSZ - 1; ++k) w[k] = w[k + 1];
            }
        }
    }
    __syncthreads();

    // ---------------- horizontal pass: b128 LDS reads, fused compute+float4 store
    {
        const int row   = tid >> 2;        // 0..63
        const int chunk = tid & 3;         // 0..3
        const int xl    = chunk * HCHUNK;  // 0,24,48,72 -> 16B aligned

        float v[HREAD]; // 48 floats, loaded as 12 x ds_read_b128
        const float4* lp = (const float4*)&inter[row * LDS_STRIDE + xl];
        #pragma unroll
        for (int i = 0; i < HREAD / 4; ++i) {
            float4 t = lp[i];
            v[4 * i + 0] = t.x; v[4 * i + 1] = t.y;
            v[4 * i + 2] = t.z; v[4 * i + 3] = t.w;
        }

        const size_t rowbase = (size_t)(y0 + row) * IMG_W;
        const int gx0 = x0 + xl;
        #pragma unroll
        for (int j4 = 0; j4 < HCHUNK / 4; ++j4) {   // fuse compute+store: live accs = 4
            float4 o;
            #pragma unroll
            for (int e = 0; e < 4; ++e) {
                const int j = 4 * j4 + e;
                float a = 0.f;
                #pragma unroll
                for (int k = 0; k < KSZ; ++k)
                    a += kW[k] * v[j + k];
                ((float*)&o)[e] = a;
            }
            const int gx = gx0 + 4 * j4;            // multiple of 4
            if (gx < IMG_W)
                *(float4*)&dst[rowbase + gx] = o;
        }
    }
}

extern "C" void kernel_launch(void* const* d_in, const int* in_sizes, int n_in,
                              void* d_out, int out_size, void* d_ws, size_t ws_size,
                              hipStream_t stream)
{
    const float* img = (const float*)d_in[0];
    float* out = (float*)d_out;

    dim3 grid((IMG_W + TILE_W - 1) / TILE_W,  // 43
              IMG_H / TILE_H,                 // 64
              N_CH);                          // 3
    dim3 block(256);
    gauss_blur_fused<<<grid, block, 0, stream>>>(img, out);
}